// Round 7
// baseline (914.415 us; speedup 1.0000x reference)
//
#include <hip/hip_runtime.h>
#include <hip/hip_bf16.h>
#include <math.h>

#define BB 64
#define NN 256
#define DD 768
#define GG 300
#define KK 10
#define NEGV -9e15f

typedef __attribute__((ext_vector_type(8)))  short short8;
typedef __attribute__((ext_vector_type(4)))  short short4v;
typedef __attribute__((ext_vector_type(16))) float f32x16;

static __device__ __forceinline__ short f2bf(float f){
  __hip_bfloat16 b = __float2bfloat16(f);
  return __builtin_bit_cast(short, b);
}

// block reduction (blockDim multiple of 64, <=256). s must have >=4 floats.
__device__ __forceinline__ float blkReduceSum(float v, float* s){
  for(int o=32;o>0;o>>=1) v += __shfl_down(v,o,64);
  int nw = blockDim.x>>6;
  __syncthreads();
  if((threadIdx.x&63)==0) s[threadIdx.x>>6]=v;
  __syncthreads();
  float r=s[0];
  for(int i=1;i<nw;i++) r+=s[i];
  return r;
}

// ---------------------------------------------------------------------------
// Semantic prep stage A: arep[b][d] = masked mean of h over nodes.
// ---------------------------------------------------------------------------
__global__ __launch_bounds__(256) void k_arep(const float* __restrict__ h,
    const float* __restrict__ amask, float* __restrict__ arep){
  int b = blockIdx.x, tid = threadIdx.x;
  int d = blockIdx.y*256 + tid;
  __shared__ float s_mask[NN];
  __shared__ float s_red[4];
  s_mask[tid] = amask[b*NN+tid];
  float cnt = blkReduceSum(s_mask[tid], s_red);
  const float* hb = h + (size_t)b*NN*DD + d;
  float a = 0.f;
  #pragma unroll 8
  for(int n=0;n<NN;n++) a += hb[(size_t)n*DD] * s_mask[n];
  arep[b*DD + d] = a/(cnt+1e-8f);
}

// ---------------------------------------------------------------------------
// Semantic prep stage B: sim[b][n] = cos(h[b,n,:], arep[b,:]).
// ---------------------------------------------------------------------------
__global__ __launch_bounds__(256) void k_sim(const float* __restrict__ h,
    const float* __restrict__ arep, float* __restrict__ sim){
  int b = blockIdx.x, tid = threadIdx.x;
  int lane = tid&63, w = tid>>6;
  __shared__ __align__(16) float s_a[DD];
  __shared__ float s_red[4];
  float pa = 0.f;
  for(int d=tid; d<DD; d+=256){ float v = arep[b*DD+d]; s_a[d]=v; pa += v*v; }
  float na = blkReduceSum(pa, s_red);
  float nac = fmaxf(sqrtf(na), 1e-12f);
  int node = blockIdx.y*4 + w;
  const float* hr = h + ((size_t)b*NN+node)*DD;
  float dot=0.f, nn=0.f;
  #pragma unroll
  for(int q=0;q<3;q++){
    int c = lane*4 + q*256;
    float4 hv = *(const float4*)(hr + c);
    float4 av = *(const float4*)(s_a + c);
    dot += hv.x*av.x + hv.y*av.y + hv.z*av.z + hv.w*av.w;
    nn  += hv.x*hv.x + hv.y*hv.y + hv.z*hv.z + hv.w*hv.w;
  }
  for(int o=32;o>0;o>>=1){ dot += __shfl_down(dot,o,64); nn += __shfl_down(nn,o,64); }
  if(lane==0){
    nn = fmaxf(sqrtf(nn), 1e-12f);
    sim[b*NN+node] = dot/(nn*nac);
  }
}

// ---------------------------------------------------------------------------
// Semantic prep stage C: top-K per batch (stable tie-break).
// ---------------------------------------------------------------------------
__global__ __launch_bounds__(256) void k_topk(const float* __restrict__ sim,
    float* __restrict__ vout, float* __restrict__ Sout){
  int b = blockIdx.x, tid = threadIdx.x;
  __shared__ float s_bv[4]; __shared__ int s_bi[4];
  __shared__ float s_tv[KK]; __shared__ int s_ti[KK];
  __shared__ float s_v[NN];
  float v = sim[b*NN+tid];
  int lane = tid&63, w = tid>>6;
  for(int k=0;k<KK;k++){
    float bv = v; int bi_ = tid;
    for(int o=32;o>0;o>>=1){
      float ov = __shfl_down(bv,o,64); int oi = __shfl_down(bi_,o,64);
      if(ov>bv || (ov==bv && oi<bi_)){ bv=ov; bi_=oi; }
    }
    if(lane==0){ s_bv[w]=bv; s_bi[w]=bi_; }
    __syncthreads();
    float gb = s_bv[0]; int gi = s_bi[0];
    for(int i=1;i<4;i++){ if(s_bv[i]>gb || (s_bv[i]==gb && s_bi[i]<gi)){ gb=s_bv[i]; gi=s_bi[i]; } }
    if(tid==0){ s_tv[k]=gb; s_ti[k]=gi; }
    if(tid==gi) v = -1e30f;
    __syncthreads();
  }
  s_v[tid]=0.f;
  __syncthreads();
  if(tid<KK) s_v[s_ti[tid]] = s_tv[tid];
  __syncthreads();
  float S=0.f;
  for(int k=0;k<KK;k++) S += s_tv[k];
  vout[b*NN+tid] = s_v[tid];
  if(tid==0) Sout[b] = S;
}

// ---------------------------------------------------------------------------
// Weight cast+transpose+pad: dst[n][k] (bf16, [NPAD][KPAD]) from W[k][300].
// ---------------------------------------------------------------------------
__global__ __launch_bounds__(256) void k_wcast(const float* __restrict__ W1,
    const float* __restrict__ W2, short* __restrict__ dst,
    int K, int KPAD, int NPAD, int n2off){
  int idx = blockIdx.x*256 + threadIdx.x;
  if(idx >= NPAD*KPAD) return;
  int n = idx / KPAD, k = idx % KPAD;
  float v = 0.f;
  if(k < K){
    if(n < 300) v = W1[(size_t)k*300 + n];
    else if(W2 && n >= n2off && n < n2off+300) v = W2[(size_t)k*300 + (n - n2off)];
  }
  dst[idx] = f2bf(v);
}

// ---------------------------------------------------------------------------
// Wh transpose for attention MFMA: WhT[b][n(320)][j(256)] bf16 from
// Wh[b*256+j][300] f32. Block = (batch, 64-j chunk); LDS tile both-side
// coalesced. Cols 300..319 zero-filled.
// ---------------------------------------------------------------------------
__global__ __launch_bounds__(256) void k_whT(const float* __restrict__ Wh,
    short* __restrict__ WhT){
  __shared__ short s_t[64][308];
  int b = blockIdx.x, j0 = blockIdx.y*64, tid = threadIdx.x;
  for(int c=tid; c<64*300; c+=256){
    int r = c/300, n = c - r*300;
    s_t[r][n] = f2bf(Wh[((size_t)(b*NN + j0 + r))*GG + n]);
  }
  __syncthreads();
  for(int c=tid; c<320*64; c+=256){
    int n = c>>6, jj = c&63;
    WhT[((size_t)b*320 + n)*256 + j0 + jj] = (n<GG) ? s_t[jj][n] : 0;
  }
}

// ---------------------------------------------------------------------------
// MFMA GEMM: Y = X @ Wt^T, Wt[NPAD][KPAD] bf16 (pre-transposed).
// BM=64, BN=320, BK=32; mfma_f32_32x32x16_bf16, verified layouts.
// MODE 0: Y1 = acc + posemb[positions[row]][n]
// MODE 1: + dual half: Y2 = acc + tvec[n-320]
// MODE 2: Y1 = relu(acc + tvec[n])   (fusion -> d_out)
// ---------------------------------------------------------------------------
template<int KPAD, int MODE, typename XT>
__global__ __launch_bounds__(256) void k_gemm(const XT* __restrict__ X,
    const short* __restrict__ Bt, const float* __restrict__ posemb,
    const int* __restrict__ positions, const float* __restrict__ tvec,
    float* __restrict__ Y1, float* __restrict__ Y2){
  __shared__ __align__(16) short sX[64*40];
  __shared__ __align__(16) short sB[320*40];
  const int tid = threadIdx.x;
  const int lane = tid & 63, wave = tid >> 6;
  const int rgrp = wave & 1, cgrp = wave >> 1;
  const int row0 = blockIdx.x * 64;
  const int ncol0 = blockIdx.y * 320;
  const int lo = lane & 31, hi = lane >> 5;

  f32x16 acc[5];
  #pragma unroll
  for(int t=0;t<5;t++)
    #pragma unroll
    for(int i=0;i<16;i++) acc[t][i] = 0.f;

  for(int k0=0; k0<KPAD; k0+=32){
    __syncthreads();
    if constexpr (sizeof(XT)==4){
      #pragma unroll
      for(int c=tid; c<512; c+=256){
        int r=c>>3, cc=c&7;
        float4 v = *(const float4*)(X + (size_t)(row0+r)*KPAD + k0 + cc*4);
        short4v s; s.x=f2bf(v.x); s.y=f2bf(v.y); s.z=f2bf(v.z); s.w=f2bf(v.w);
        *(short4v*)(sX + r*40 + cc*4) = s;
      }
    } else {
      if(tid < 256){
        int r=tid>>2, cc=tid&3;
        *(short8*)(sX + r*40 + cc*8) = *(const short8*)(X + (size_t)(row0+r)*KPAD + k0 + cc*8);
      }
    }
    #pragma unroll
    for(int c=tid; c<1280; c+=256){
      int r=c>>2, cc=c&3;
      *(short8*)(sB + r*40 + cc*8) = *(const short8*)(Bt + (size_t)(ncol0+r)*KPAD + k0 + cc*8);
    }
    __syncthreads();
    #pragma unroll
    for(int ss=0; ss<2; ss++){
      int kb = ss*16 + hi*8;
      short8 a = *(const short8*)(sX + (rgrp*32 + lo)*40 + kb);
      #pragma unroll
      for(int t=0;t<5;t++){
        short8 b = *(const short8*)(sB + (cgrp*160 + t*32 + lo)*40 + kb);
        acc[t] = __builtin_amdgcn_mfma_f32_32x32x16_bf16(a, b, acc[t], 0, 0, 0);
      }
    }
  }

  #pragma unroll
  for(int r=0;r<16;r++){
    int row = row0 + rgrp*32 + (r&3) + 8*(r>>2) + 4*hi;
    int p = 0;
    if(MODE!=2) p = positions[row];
    #pragma unroll
    for(int t=0;t<5;t++){
      int nc = ncol0 + cgrp*160 + t*32 + lo;
      float v = acc[t][r];
      if(MODE==2){
        if(nc < 300) Y1[(size_t)row*300 + nc] = fmaxf(v + tvec[nc], 0.f);
      } else {
        if(nc < 300) Y1[(size_t)row*300 + nc] = v + posemb[(size_t)p*300 + nc];
        else if(MODE==1 && nc>=320 && nc<620) Y2[(size_t)row*300 + (nc-320)] = v + tvec[nc-320];
      }
    }
  }
}

// ---------------------------------------------------------------------------
// f1/f2: one wave per row
// ---------------------------------------------------------------------------
__global__ __launch_bounds__(256) void k_f1f2(const float* __restrict__ Wh,
    const float* __restrict__ a1, const float* __restrict__ a2,
    float* __restrict__ f1, float* __restrict__ f2){
  int row = blockIdx.x*4 + (threadIdx.x>>6);
  int lane = threadIdx.x&63;
  const float* wr = Wh + (size_t)row*GG;
  float s1=0.f, s2=0.f;
  for(int c=lane;c<GG;c+=64){ float wv=wr[c]; s1 += wv*a1[c]; s2 += wv*a2[c]; }
  for(int o=32;o>0;o>>=1){ s1+=__shfl_down(s1,o,64); s2+=__shfl_down(s2,o,64); }
  if(lane==0){ f1[row]=s1; f2[row]=s2; }
}

// ---------------------------------------------------------------------------
// Fused attention (MFMA) + residual + LayerNorm + ReLU.
// Block = (batch, 64-row tile), 256 thr / 4 waves.
// Phase 1: softmax wave-per-row -> P bf16 in LDS, row-major [64][264].
// Phase 2: MFMA hp = P @ Wh via WhT bf16 [b][320][256] staged like k_gemm.
// Phase 3: in-register residual+LN+ReLU with shfl_xor(lo) + LDS cross-wave.
// ---------------------------------------------------------------------------
template<bool SEM>
__global__ __launch_bounds__(256) void k_attn_ln(
    const short* __restrict__ WhT,
    const float* __restrict__ f1, const float* __restrict__ f2,
    const int* __restrict__ adjI, const float* __restrict__ vvec,
    const float* __restrict__ Svec,
    const float* __restrict__ res, int res_ld,
    const float* __restrict__ g, const float* __restrict__ bt,
    float* __restrict__ f32out, int f32_ld, int f32pad,
    short* __restrict__ bfout, int bf_ld, int bf_off, int bfpad){
  int b = blockIdx.x, i0 = blockIdx.y*64, tid = threadIdx.x;
  int lane = tid&63, wave = tid>>6;
  int lo = lane&31, hi = lane>>5;
  int rgrp = wave&1, cgrp = wave>>1;

  __shared__ float s_f2[NN];
  __shared__ float s_v[NN];
  __shared__ __align__(16) short sP[64][264];
  __shared__ __align__(16) short sB[320*40];
  __shared__ float sRed[64][2];

  s_f2[tid] = f2[b*NN+tid];
  float S = 0.f;
  if(SEM){ s_v[tid] = vvec[b*NN+tid]; S = Svec[b]; }
  __syncthreads();

  // ---- softmax: wave handles rows wave*16 .. wave*16+15; lane owns 4 consec j
  for(int rr=0; rr<16; rr++){
    int r = wave*16 + rr;
    int i = i0 + r;
    float fi = f1[b*NN+i];
    float vi = SEM ? s_v[i] : 0.f;
    float denom = SEM ? (0.5f*((float)NN*vi + S) + 1.f + 1e-8f) : 0.f;
    int j0 = lane*4;
    int4 adj4;
    if(!SEM) adj4 = *(const int4*)(adjI + ((size_t)b*NN+i)*NN + j0);
    float e[4]; float mx = -INFINITY;
    #pragma unroll
    for(int q=0;q<4;q++){
      int j = j0+q;
      float ee = fi + s_f2[j];
      ee = ee>0.f ? ee : 0.2f*ee;
      bool m;
      if(SEM){
        float val = 0.5f*(vi + s_v[j]) + (i==j ? 1.f : 0.f);
        m = (denom > 0.f) ? (val > 0.f) : (val < 0.f);
      } else {
        m = ((&adj4.x)[q]) > 0;
      }
      ee = m ? ee : NEGV;
      e[q]=ee; mx = fmaxf(mx, ee);
    }
    for(int o=32;o>0;o>>=1) mx = fmaxf(mx, __shfl_xor(mx,o,64));
    float sm = 0.f;
    #pragma unroll
    for(int q=0;q<4;q++){ e[q] = expf(e[q]-mx); sm += e[q]; }
    for(int o=32;o>0;o>>=1) sm += __shfl_xor(sm,o,64);
    float inv = 1.f/sm;
    short4v p4;
    p4.x=f2bf(e[0]*inv); p4.y=f2bf(e[1]*inv); p4.z=f2bf(e[2]*inv); p4.w=f2bf(e[3]*inv);
    *(short4v*)&sP[r][j0] = p4;
  }

  // ---- MFMA: acc[64x320] = P[64x256] @ Wh[256x320] (via WhT) ----
  f32x16 acc[5];
  #pragma unroll
  for(int t=0;t<5;t++)
    #pragma unroll
    for(int i=0;i<16;i++) acc[t][i] = 0.f;

  const short* wtb = WhT + (size_t)b*320*256;
  for(int k0=0; k0<256; k0+=32){
    __syncthreads();
    #pragma unroll
    for(int c=tid; c<1280; c+=256){
      int r=c>>2, cc=c&3;
      *(short8*)(sB + r*40 + cc*8) = *(const short8*)(wtb + (size_t)r*256 + k0 + cc*8);
    }
    __syncthreads();
    #pragma unroll
    for(int ss=0; ss<2; ss++){
      short8 a = *(const short8*)&sP[rgrp*32 + lo][k0 + ss*16 + hi*8];
      #pragma unroll
      for(int t=0;t<5;t++){
        short8 bb = *(const short8*)(sB + (cgrp*160 + t*32 + lo)*40 + ss*16 + hi*8);
        acc[t] = __builtin_amdgcn_mfma_f32_32x32x16_bf16(a, bb, acc[t], 0, 0, 0);
      }
    }
  }

  // ---- residual add + row sums (overwrite acc with x) ----
  #pragma unroll
  for(int r=0;r<16;r++){
    int lr = rgrp*32 + (r&3) + 8*(r>>2) + 4*hi;
    size_t ro = (size_t)(b*NN + i0 + lr)*res_ld;
    float s = 0.f;
    #pragma unroll
    for(int t=0;t<5;t++){
      int nc = cgrp*160 + t*32 + lo;
      float x = (nc < GG) ? (acc[t][r] + res[ro + nc]) : 0.f;
      acc[t][r] = x; s += x;
    }
    for(int o=1;o<32;o<<=1) s += __shfl_xor(s,o,64);
    if(lo==0) sRed[lr][cgrp] = s;
  }
  __syncthreads();
  float mean[16];
  #pragma unroll
  for(int r=0;r<16;r++){
    int lr = rgrp*32 + (r&3) + 8*(r>>2) + 4*hi;
    mean[r] = (sRed[lr][0] + sRed[lr][1]) * (1.f/(float)GG);
  }
  __syncthreads();
  #pragma unroll
  for(int r=0;r<16;r++){
    int lr = rgrp*32 + (r&3) + 8*(r>>2) + 4*hi;
    float s = 0.f;
    #pragma unroll
    for(int t=0;t<5;t++){
      int nc = cgrp*160 + t*32 + lo;
      if(nc < GG){ float d = acc[t][r] - mean[r]; s += d*d; }
    }
    for(int o=1;o<32;o<<=1) s += __shfl_xor(s,o,64);
    if(lo==0) sRed[lr][cgrp] = s;
  }
  __syncthreads();
  #pragma unroll
  for(int r=0;r<16;r++){
    int lr = rgrp*32 + (r&3) + 8*(r>>2) + 4*hi;
    int grow = b*NN + i0 + lr;
    float iv = 1.0f/sqrtf((sRed[lr][0]+sRed[lr][1])/(float)GG + 1e-5f);
    float mn = mean[r];
    #pragma unroll
    for(int t=0;t<5;t++){
      int nc = cgrp*160 + t*32 + lo;
      if(nc < GG){
        float y = fmaxf((acc[t][r]-mn)*iv*g[nc] + bt[nc], 0.f);
        if(f32out) f32out[(size_t)grow*f32_ld + nc] = y;
        if(bfout)  bfout[(size_t)grow*bf_ld + bf_off + nc] = f2bf(y);
      } else {
        if(f32out && nc < f32pad) f32out[(size_t)grow*f32_ld + nc] = 0.f;
        if(bfout  && nc < bfpad)  bfout[(size_t)grow*bf_ld + bf_off + nc] = 0;
      }
    }
  }
}

// ---------------------------------------------------------------------------
extern "C" void kernel_launch(void* const* d_in, const int* in_sizes, int n_in,
                              void* d_out, int out_size, void* d_ws, size_t ws_size,
                              hipStream_t stream){
  const float* h     = (const float*)d_in[0];
  const float* amask = (const float*)d_in[1];
  const float *syn0_W=(const float*)d_in[2], *syn0_a1=(const float*)d_in[3], *syn0_a2=(const float*)d_in[4],
              *syn0_pos=(const float*)d_in[5], *syn0_tW=(const float*)d_in[6], *syn0_tb=(const float*)d_in[7],
              *syn0_g=(const float*)d_in[8], *syn0_b=(const float*)d_in[9];
  const float *syn1_W=(const float*)d_in[10], *syn1_a1=(const float*)d_in[11], *syn1_a2=(const float*)d_in[12],
              *syn1_pos=(const float*)d_in[13], *syn1_g=(const float*)d_in[14], *syn1_b=(const float*)d_in[15];
  const float *sem0_W=(const float*)d_in[16], *sem0_a1=(const float*)d_in[17], *sem0_a2=(const float*)d_in[18],
              *sem0_pos=(const float*)d_in[19], *sem0_tW=(const float*)d_in[20], *sem0_tb=(const float*)d_in[21],
              *sem0_g=(const float*)d_in[22], *sem0_b=(const float*)d_in[23];
  const float *sem1_W=(const float*)d_in[24], *sem1_a1=(const float*)d_in[25], *sem1_a2=(const float*)d_in[26],
              *sem1_pos=(const float*)d_in[27], *sem1_g=(const float*)d_in[28], *sem1_b=(const float*)d_in[29];
  const float *fus_W=(const float*)d_in[30], *fus_b=(const float*)d_in[31];
  const int* synadj    = (const int*)d_in[32];
  const int* positions = (const int*)d_in[33];
  float* out = (float*)d_out;

  float* ws   = (float*)d_ws;
  float* vvec = ws;                  // 16384
  float* Svec = vvec + 16384;        // 64
  float* f1   = Svec + 64;           // 16384
  float* f2   = f1 + 16384;          // 16384
  float* arep = f2 + 16384;          // 49152
  float* simb = arep + 49152;        // 16384
  float* Wh   = simb + 16384;        // 4,915,200 (f32, [16384][300])
  float* T1   = Wh + 4915200;        // residual layer0 (stride 300)
  float* X1   = T1 + 4915200;        // LN0 out f32, stride 320 (residual layer1)
  short* Xb      = (short*)(X1 + 5242880);  // LN0 out bf16 [16384][320]
  short* WhT     = Xb + 5242880;     // [64][320][256] bf16
  short* Xf      = WhT + 5242880;    // fusion input [16384][608] bf16
  short* Wt_syn0 = Xf + 9961472;     // [640][768]
  short* Wt_sem0 = Wt_syn0 + 491520; // [640][768]
  short* Wt_syn1 = Wt_sem0 + 491520; // [320][320]
  short* Wt_sem1 = Wt_syn1 + 102400; // [320][320]
  short* Wt_fus  = Wt_sem1 + 102400; // [320][608]

  dim3 gAttn(BB, 4);
  dim3 gWT(BB, 4);
  dim3 gG2(256, 2), gG1(256, 1);
  int gF = BB*NN/4;   // 4096

  // semantic prep
  k_arep<<<dim3(BB,3),256,0,stream>>>(h, amask, arep);
  k_sim <<<dim3(BB,64),256,0,stream>>>(h, arep, simb);
  k_topk<<<BB,256,0,stream>>>(simb, vvec, Svec);

  k_wcast<<<1920,256,0,stream>>>(syn0_W, syn0_tW, Wt_syn0, 768, 768, 640, 320);
  k_wcast<<<1920,256,0,stream>>>(sem0_W, sem0_tW, Wt_sem0, 768, 768, 640, 320);
  k_wcast<<< 400,256,0,stream>>>(syn1_W, nullptr, Wt_syn1, 300, 320, 320, 0);
  k_wcast<<< 400,256,0,stream>>>(sem1_W, nullptr, Wt_sem1, 300, 320, 320, 0);
  k_wcast<<< 760,256,0,stream>>>(fus_W,  nullptr, Wt_fus,  600, 608, 320, 0);

  // syntactic layer 0
  k_gemm<768,1,float><<<gG2,256,0,stream>>>(h, Wt_syn0, syn0_pos, positions, syn0_tb, Wh, T1);
  k_f1f2<<<gF,256,0,stream>>>(Wh, syn0_a1, syn0_a2, f1, f2);
  k_whT<<<gWT,256,0,stream>>>(Wh, WhT);
  k_attn_ln<false><<<gAttn,256,0,stream>>>(WhT, f1, f2, synadj, nullptr, nullptr,
      T1, 300, syn0_g, syn0_b, X1, 320, 320, Xb, 320, 0, 320);
  // syntactic layer 1 (identity residual X1) -> Xf cols [0,300)
  k_gemm<320,0,short><<<gG1,256,0,stream>>>(Xb, Wt_syn1, syn1_pos, positions, nullptr, Wh, nullptr);
  k_f1f2<<<gF,256,0,stream>>>(Wh, syn1_a1, syn1_a2, f1, f2);
  k_whT<<<gWT,256,0,stream>>>(Wh, WhT);
  k_attn_ln<false><<<gAttn,256,0,stream>>>(WhT, f1, f2, synadj, nullptr, nullptr,
      X1, 320, syn1_g, syn1_b, nullptr, 0, 0, Xf, 608, 0, 300);

  // semantic layer 0
  k_gemm<768,1,float><<<gG2,256,0,stream>>>(h, Wt_sem0, sem0_pos, positions, sem0_tb, Wh, T1);
  k_f1f2<<<gF,256,0,stream>>>(Wh, sem0_a1, sem0_a2, f1, f2);
  k_whT<<<gWT,256,0,stream>>>(Wh, WhT);
  k_attn_ln<true><<<gAttn,256,0,stream>>>(WhT, f1, f2, nullptr, vvec, Svec,
      T1, 300, sem0_g, sem0_b, X1, 320, 320, Xb, 320, 0, 320);
  // semantic layer 1 -> Xf cols [300,600), zero-pad [600,608)
  k_gemm<320,0,short><<<gG1,256,0,stream>>>(Xb, Wt_sem1, sem1_pos, positions, nullptr, Wh, nullptr);
  k_f1f2<<<gF,256,0,stream>>>(Wh, sem1_a1, sem1_a2, f1, f2);
  k_whT<<<gWT,256,0,stream>>>(Wh, WhT);
  k_attn_ln<true><<<gAttn,256,0,stream>>>(WhT, f1, f2, nullptr, vvec, Svec,
      X1, 320, sem1_g, sem1_b, nullptr, 0, 0, Xf, 608, 300, 308);

  // fusion: out = relu(concat @ fus_W + fus_b)
  k_gemm<608,2,short><<<gG1,256,0,stream>>>(Xf, Wt_fus, nullptr, nullptr, fus_b, out, nullptr);
}

// Round 8
// 749.806 us; speedup vs baseline: 1.2195x; 1.2195x over previous
//
#include <hip/hip_runtime.h>
#include <hip/hip_bf16.h>
#include <math.h>

#define BB 64
#define NN 256
#define DD 768
#define GG 300
#define KK 10
#define NEGV -9e15f

typedef __attribute__((ext_vector_type(8)))  short short8;
typedef __attribute__((ext_vector_type(4)))  short short4v;
typedef __attribute__((ext_vector_type(16))) float f32x16;

static __device__ __forceinline__ short f2bf(float f){
  __hip_bfloat16 b = __float2bfloat16(f);
  return __builtin_bit_cast(short, b);
}
static __device__ __forceinline__ float bf2f(short s){
  return __bfloat162float(__builtin_bit_cast(__hip_bfloat16, s));
}

__device__ __forceinline__ float blkReduceSum(float v, float* s){
  for(int o=32;o>0;o>>=1) v += __shfl_down(v,o,64);
  int nw = blockDim.x>>6;
  __syncthreads();
  if((threadIdx.x&63)==0) s[threadIdx.x>>6]=v;
  __syncthreads();
  float r=s[0];
  for(int i=1;i<nw;i++) r+=s[i];
  return r;
}

// ---------------------------------------------------------------------------
// Semantic prep A: arep[b][d] = masked mean of h over nodes. grid (64,3).
// ---------------------------------------------------------------------------
__global__ __launch_bounds__(256) void k_arep(const float* __restrict__ h,
    const float* __restrict__ amask, float* __restrict__ arep){
  int b = blockIdx.x, tid = threadIdx.x;
  int d = blockIdx.y*256 + tid;
  __shared__ float s_mask[NN];
  __shared__ float s_red[4];
  s_mask[tid] = amask[b*NN+tid];
  float cnt = blkReduceSum(s_mask[tid], s_red);
  const float* hb = h + (size_t)b*NN*DD + d;
  float a = 0.f;
  #pragma unroll 8
  for(int n=0;n<NN;n++) a += hb[(size_t)n*DD] * s_mask[n];
  arep[b*DD + d] = a/(cnt+1e-8f);
}

// ---------------------------------------------------------------------------
// Semantic prep B: sim[b][n] = cos(h[b,n,:], arep[b,:]). grid (64,64).
// ---------------------------------------------------------------------------
__global__ __launch_bounds__(256) void k_sim(const float* __restrict__ h,
    const float* __restrict__ arep, float* __restrict__ sim){
  int b = blockIdx.x, tid = threadIdx.x;
  int lane = tid&63, w = tid>>6;
  __shared__ __align__(16) float s_a[DD];
  __shared__ float s_red[4];
  float pa = 0.f;
  for(int d=tid; d<DD; d+=256){ float v = arep[b*DD+d]; s_a[d]=v; pa += v*v; }
  float na = blkReduceSum(pa, s_red);
  float nac = fmaxf(sqrtf(na), 1e-12f);
  int node = blockIdx.y*4 + w;
  const float* hr = h + ((size_t)b*NN+node)*DD;
  float dot=0.f, nn=0.f;
  #pragma unroll
  for(int q=0;q<3;q++){
    int c = lane*4 + q*256;
    float4 hv = *(const float4*)(hr + c);
    float4 av = *(const float4*)(s_a + c);
    dot += hv.x*av.x + hv.y*av.y + hv.z*av.z + hv.w*av.w;
    nn  += hv.x*hv.x + hv.y*hv.y + hv.z*hv.z + hv.w*hv.w;
  }
  for(int o=32;o>0;o>>=1){ dot += __shfl_down(dot,o,64); nn += __shfl_down(nn,o,64); }
  if(lane==0){
    nn = fmaxf(sqrtf(nn), 1e-12f);
    sim[b*NN+node] = dot/(nn*nac);
  }
}

// ---------------------------------------------------------------------------
// Semantic prep C: stable top-K per batch -> scattered v[b,:], S[b].
// ---------------------------------------------------------------------------
__global__ __launch_bounds__(256) void k_topk(const float* __restrict__ sim,
    float* __restrict__ vout, float* __restrict__ Sout){
  int b = blockIdx.x, tid = threadIdx.x;
  __shared__ float s_bv[4]; __shared__ int s_bi[4];
  __shared__ float s_tv[KK]; __shared__ int s_ti[KK];
  __shared__ float s_v[NN];
  float v = sim[b*NN+tid];
  int lane = tid&63, w = tid>>6;
  for(int k=0;k<KK;k++){
    float bv = v; int bi_ = tid;
    for(int o=32;o>0;o>>=1){
      float ov = __shfl_down(bv,o,64); int oi = __shfl_down(bi_,o,64);
      if(ov>bv || (ov==bv && oi<bi_)){ bv=ov; bi_=oi; }
    }
    if(lane==0){ s_bv[w]=bv; s_bi[w]=bi_; }
    __syncthreads();
    float gb = s_bv[0]; int gi = s_bi[0];
    for(int i=1;i<4;i++){ if(s_bv[i]>gb || (s_bv[i]==gb && s_bi[i]<gi)){ gb=s_bv[i]; gi=s_bi[i]; } }
    if(tid==0){ s_tv[k]=gb; s_ti[k]=gi; }
    if(tid==gi) v = -1e30f;
    __syncthreads();
  }
  s_v[tid]=0.f;
  __syncthreads();
  if(tid<KK) s_v[s_ti[tid]] = s_tv[tid];
  __syncthreads();
  float S=0.f;
  for(int k=0;k<KK;k++) S += s_tv[k];
  vout[b*NN+tid] = s_v[tid];
  if(tid==0) Sout[b] = S;
}

// ---------------------------------------------------------------------------
// Weight cast+transpose+pad: dst[n][k] bf16 [NPAD][KPAD] from W[k][300].
// ---------------------------------------------------------------------------
__global__ __launch_bounds__(256) void k_wcast(const float* __restrict__ W1,
    short* __restrict__ dst, int K, int KPAD, int NPAD){
  int idx = blockIdx.x*256 + threadIdx.x;
  if(idx >= NPAD*KPAD) return;
  int n = idx / KPAD, k = idx % KPAD;
  float v = (k < K && n < 300) ? W1[(size_t)k*300 + n] : 0.f;
  dst[idx] = f2bf(v);
}

// Quad pack for merged layer-0 GEMM: dst [1280][768], segments of 320 cols:
// {syn0_W, syn0_tW, sem0_W, sem0_tW}, each 300 used + 20 zero pad.
__global__ __launch_bounds__(256) void k_wcast4(const float* __restrict__ W0,
    const float* __restrict__ W1, const float* __restrict__ W2,
    const float* __restrict__ W3, short* __restrict__ dst){
  int idx = blockIdx.x*256 + threadIdx.x;
  if(idx >= 1280*768) return;
  int n = idx / 768, k = idx - (n*768);
  int seg = n >> 8; seg = n/320; int nl = n - seg*320;
  const float* src = (seg==0)?W0 : (seg==1)?W1 : (seg==2)?W2 : W3;
  float v = (nl<300) ? src[(size_t)k*300 + nl] : 0.f;
  dst[idx] = f2bf(v);
}

// ---------------------------------------------------------------------------
// MFMA GEMM with register-prefetch pipeline + per-block K-phase stagger.
// Y = X[M][KPAD] @ Wt^T, Wt[NPAD][KPAD] bf16. BM=64, BN=320, BK=32.
// MODE 0: whb_syn[row*320+nc] = bf16(acc + pos_syn[positions[row]*300+nc])
// MODE 2: outf[row*300+nc] = relu(acc + tb_syn[nc])            (fusion)
// MODE 3: merged quad; blockIdx.y = segment:
//   0: whb_syn + pos_syn | 1: t1_syn + tb_syn | 2: whb_sem + pos_sem | 3: t1_sem + tb_sem
// ---------------------------------------------------------------------------
template<int KPAD, int MODE, typename XT>
__global__ __launch_bounds__(256) void k_gemm(const XT* __restrict__ X,
    const short* __restrict__ Bt, const int* __restrict__ positions,
    const float* __restrict__ pos_syn, const float* __restrict__ pos_sem,
    const float* __restrict__ tb_syn, const float* __restrict__ tb_sem,
    short* __restrict__ whb_syn, short* __restrict__ whb_sem,
    float* __restrict__ t1_syn, float* __restrict__ t1_sem,
    float* __restrict__ outf){
  __shared__ __align__(16) short sX[64*40];
  __shared__ __align__(16) short sB[320*40];
  const int tid = threadIdx.x;
  const int lane = tid & 63, wave = tid >> 6;
  const int rgrp = wave & 1, cgrp = wave >> 1;
  const int row0 = blockIdx.x * 64;
  const int ncol0 = blockIdx.y * 320;
  const int lo = lane & 31, hi = lane >> 5;
  constexpr int NIT = KPAD/32;
  const int phase = (int)((blockIdx.x*7 + blockIdx.y*3) % NIT);

  f32x16 acc[5];
  #pragma unroll
  for(int t=0;t<5;t++)
    #pragma unroll
    for(int i=0;i<16;i++) acc[t][i] = 0.f;

  float4 rx0, rx1; short8 rxb; short8 rb[5];

  // prologue load (iteration 0)
  {
    int v0 = phase; int k0 = v0*32;
    if constexpr (sizeof(XT)==4){
      int c0=tid, c1=tid+256;
      rx0 = *(const float4*)(X + (size_t)(row0+(c0>>3))*KPAD + k0 + (c0&7)*4);
      rx1 = *(const float4*)(X + (size_t)(row0+(c1>>3))*KPAD + k0 + (c1&7)*4);
    } else {
      rxb = *(const short8*)(X + (size_t)(row0+(tid>>2))*KPAD + k0 + (tid&3)*8);
    }
    #pragma unroll
    for(int u=0;u<5;u++){
      int c = tid + u*256; int r=c>>2, cc=c&3;
      rb[u] = *(const short8*)(Bt + (size_t)(ncol0+r)*KPAD + k0 + cc*8);
    }
  }

  for(int it=0; it<NIT; it++){
    int kv = it + phase; if(kv >= NIT) kv -= NIT;
    int k0 = kv*32;
    // store staged regs to LDS
    if constexpr (sizeof(XT)==4){
      { int c=tid; short4v s; s.x=f2bf(rx0.x); s.y=f2bf(rx0.y); s.z=f2bf(rx0.z); s.w=f2bf(rx0.w);
        *(short4v*)(sX + (c>>3)*40 + (c&7)*4) = s; }
      { int c=tid+256; short4v s; s.x=f2bf(rx1.x); s.y=f2bf(rx1.y); s.z=f2bf(rx1.z); s.w=f2bf(rx1.w);
        *(short4v*)(sX + (c>>3)*40 + (c&7)*4) = s; }
    } else {
      *(short8*)(sX + (tid>>2)*40 + (tid&3)*8) = rxb;
    }
    #pragma unroll
    for(int u=0;u<5;u++){
      int c = tid + u*256;
      *(short8*)(sB + (c>>2)*40 + (c&3)*8) = rb[u];
    }
    __syncthreads();
    // prefetch next iteration's tiles into registers (overlaps MFMA below)
    if(it+1 < NIT){
      int kn = it+1+phase; if(kn >= NIT) kn -= NIT;
      int k1 = kn*32;
      if constexpr (sizeof(XT)==4){
        int c0=tid, c1=tid+256;
        rx0 = *(const float4*)(X + (size_t)(row0+(c0>>3))*KPAD + k1 + (c0&7)*4);
        rx1 = *(const float4*)(X + (size_t)(row0+(c1>>3))*KPAD + k1 + (c1&7)*4);
      } else {
        rxb = *(const short8*)(X + (size_t)(row0+(tid>>2))*KPAD + k1 + (tid&3)*8);
      }
      #pragma unroll
      for(int u=0;u<5;u++){
        int c = tid + u*256; int r=c>>2, cc=c&3;
        rb[u] = *(const short8*)(Bt + (size_t)(ncol0+r)*KPAD + k1 + cc*8);
      }
    }
    // compute on k0
    #pragma unroll
    for(int ss=0; ss<2; ss++){
      int kb = ss*16 + hi*8;
      short8 a = *(const short8*)(sX + (rgrp*32 + lo)*40 + kb);
      #pragma unroll
      for(int t=0;t<5;t++){
        short8 b = *(const short8*)(sB + (cgrp*160 + t*32 + lo)*40 + kb);
        acc[t] = __builtin_amdgcn_mfma_f32_32x32x16_bf16(a, b, acc[t], 0, 0, 0);
      }
    }
    __syncthreads();
  }

  #pragma unroll
  for(int r=0;r<16;r++){
    int row = row0 + rgrp*32 + (r&3) + 8*(r>>2) + 4*hi;
    int p = (MODE!=2) ? positions[row] : 0;
    #pragma unroll
    for(int t=0;t<5;t++){
      int nc = cgrp*160 + t*32 + lo;   // 0..319 within this 320-tile
      float v = acc[t][r];
      if(nc < 300){
        if(MODE==2){
          outf[(size_t)row*300 + nc] = fmaxf(v + tb_syn[nc], 0.f);
        } else if(MODE==0){
          whb_syn[(size_t)row*320 + nc] = f2bf(v + pos_syn[(size_t)p*300 + nc]);
        } else { // MODE 3
          int seg = blockIdx.y;
          if(seg==0)      whb_syn[(size_t)row*320 + nc] = f2bf(v + pos_syn[(size_t)p*300 + nc]);
          else if(seg==1) t1_syn[(size_t)row*300 + nc]  = v + tb_syn[nc];
          else if(seg==2) whb_sem[(size_t)row*320 + nc] = f2bf(v + pos_sem[(size_t)p*300 + nc]);
          else            t1_sem[(size_t)row*300 + nc]  = v + tb_sem[nc];
        }
      }
    }
  }
}

// ---------------------------------------------------------------------------
// Wh transpose (bf16 in, stride 320) + folded f1/f2. grid (64,4).
// WhT[b][n(320)][j(256)]; f1/f2 per row via 4-lane partial dots.
// ---------------------------------------------------------------------------
__global__ __launch_bounds__(256) void k_whT(const short* __restrict__ Whb,
    const float* __restrict__ a1v, const float* __restrict__ a2v,
    short* __restrict__ WhT, float* __restrict__ f1, float* __restrict__ f2){
  __shared__ short s_t[64][308];
  int b = blockIdx.x, j0 = blockIdx.y*64, tid = threadIdx.x;
  for(int c=tid; c<64*300; c+=256){
    int r = c/300, n = c - r*300;
    s_t[r][n] = Whb[((size_t)(b*NN + j0 + r))*320 + n];
  }
  __syncthreads();
  {
    int r = tid>>2, q = tid&3;
    float s1=0.f, s2=0.f;
    for(int n=q; n<300; n+=4){
      float wv = bf2f(s_t[r][n]);
      s1 += wv*a1v[n]; s2 += wv*a2v[n];
    }
    s1 += __shfl_xor(s1,1,64); s1 += __shfl_xor(s1,2,64);
    s2 += __shfl_xor(s2,1,64); s2 += __shfl_xor(s2,2,64);
    if(q==0){ f1[b*NN+j0+r] = s1; f2[b*NN+j0+r] = s2; }
  }
  for(int c=tid; c<320*64; c+=256){
    int n = c>>6, jj = c&63;
    WhT[((size_t)b*320 + n)*256 + j0 + jj] = (n<GG) ? s_t[jj][n] : (short)0;
  }
}

// ---------------------------------------------------------------------------
// Fused attention (MFMA) + residual + LayerNorm + ReLU. grid (64,4), 256 thr.
// Softmax: thread=(row, quarter), 16 independent adj int4 loads, no-max
// (e in ~[-2,2], exp safe); UNNORMALIZED exp -> sP bf16; 1/rowsum applied to
// the accumulator after MFMA. Residual: f32 (resf) or bf16 stride-320 (resb).
// ---------------------------------------------------------------------------
template<bool SEM>
__global__ __launch_bounds__(256) void k_attn_ln(
    const short* __restrict__ WhT,
    const float* __restrict__ f1, const float* __restrict__ f2,
    const int* __restrict__ adjI, const float* __restrict__ vvec,
    const float* __restrict__ Svec,
    const float* __restrict__ resf, const short* __restrict__ resb,
    const float* __restrict__ g, const float* __restrict__ bt,
    short* __restrict__ bfout, int bf_ld, int bf_off, int bfpad){
  int b = blockIdx.x, i0 = blockIdx.y*64, tid = threadIdx.x;
  int lane = tid&63, wave = tid>>6;
  int lo = lane&31, hi = lane>>5;
  int rgrp = wave&1, cgrp = wave>>1;

  __shared__ float s_f2[NN];
  __shared__ float s_v[NN];
  __shared__ float s_inv[64];
  __shared__ float sRed[64][2];
  __shared__ __align__(16) short sP[64][264];
  __shared__ __align__(16) short sB[320*40];

  s_f2[tid] = f2[b*NN+tid];
  float S = 0.f;
  if(SEM){ s_v[tid] = vvec[b*NN+tid]; S = Svec[b]; }
  __syncthreads();

  // ---- softmax: thread = (row r, quarter q), 64 j's each, all loads indep
  {
    int r = tid>>2, q = tid&3, i = i0 + r;
    float fi = f1[b*NN+i];
    float vi = 0.f, denom = 0.f;
    if(SEM){ vi = s_v[i]; denom = 0.5f*((float)NN*vi + S) + 1.f + 1e-8f; }
    const int* arow = adjI ? (adjI + ((size_t)b*NN+i)*NN + q*64) : (const int*)0;
    float s = 0.f;
    #pragma unroll
    for(int c=0;c<8;c++){
      int jb = q*64 + c*8;
      int4 a0, a1_;
      if(!SEM){ a0 = *(const int4*)(arow + c*8); a1_ = *(const int4*)(arow + c*8 + 4); }
      short8 ps;
      #pragma unroll
      for(int k=0;k<8;k++){
        int j = jb + k;
        float ee = fi + s_f2[j];
        ee = ee>0.f ? ee : 0.2f*ee;
        bool m;
        if(SEM){
          float val = 0.5f*(vi + s_v[j]) + (i==j ? 1.f : 0.f);
          m = (denom > 0.f) ? (val > 0.f) : (val < 0.f);
        } else {
          m = ((k<4) ? (&a0.x)[k] : (&a1_.x)[k-4]) > 0;
        }
        float pv = m ? __expf(ee) : 0.f;
        s += pv;
        ps[k] = f2bf(pv);
      }
      *(short8*)&sP[r][jb] = ps;
    }
    s += __shfl_xor(s,1,64);
    s += __shfl_xor(s,2,64);
    if(q==0) s_inv[r] = 1.f/s;
  }
  __syncthreads();

  // ---- MFMA: acc[64x320] = P_unnorm[64x256] @ Wh[256x320] via WhT ----
  f32x16 acc[5];
  #pragma unroll
  for(int t=0;t<5;t++)
    #pragma unroll
    for(int i=0;i<16;i++) acc[t][i] = 0.f;

  const short* wtb = WhT + (size_t)b*320*256;
  for(int k0=0; k0<256; k0+=32){
    #pragma unroll
    for(int u=0;u<5;u++){
      int c = tid + u*256; int r=c>>2, cc=c&3;
      *(short8*)(sB + r*40 + cc*8) = *(const short8*)(wtb + (size_t)r*256 + k0 + cc*8);
    }
    __syncthreads();
    #pragma unroll
    for(int ss=0; ss<2; ss++){
      short8 a = *(const short8*)&sP[rgrp*32 + lo][k0 + ss*16 + hi*8];
      #pragma unroll
      for(int t=0;t<5;t++){
        short8 bb = *(const short8*)(sB + (cgrp*160 + t*32 + lo)*40 + ss*16 + hi*8);
        acc[t] = __builtin_amdgcn_mfma_f32_32x32x16_bf16(a, bb, acc[t], 0, 0, 0);
      }
    }
    __syncthreads();
  }

  // ---- scale by 1/rowsum, residual add, row sums ----
  #pragma unroll
  for(int r=0;r<16;r++){
    int lr = rgrp*32 + (r&3) + 8*(r>>2) + 4*hi;
    float inv_s = s_inv[lr];
    size_t grow = (size_t)(b*NN + i0 + lr);
    float sum = 0.f;
    #pragma unroll
    for(int t=0;t<5;t++){
      int nc = cgrp*160 + t*32 + lo;
      float x = 0.f;
      if(nc < GG){
        float rv = resf ? resf[grow*300 + nc] : bf2f(resb[grow*320 + nc]);
        x = acc[t][r]*inv_s + rv;
      }
      acc[t][r] = x; sum += x;
    }
    for(int o=1;o<32;o<<=1) sum += __shfl_xor(sum,o,64);
    if(lo==0) sRed[lr][cgrp] = sum;
  }
  __syncthreads();
  float mean[16];
  #pragma unroll
  for(int r=0;r<16;r++){
    int lr = rgrp*32 + (r&3) + 8*(r>>2) + 4*hi;
    mean[r] = (sRed[lr][0] + sRed[lr][1]) * (1.f/(float)GG);
  }
  __syncthreads();
  #pragma unroll
  for(int r=0;r<16;r++){
    int lr = rgrp*32 + (r&3) + 8*(r>>2) + 4*hi;
    float s = 0.f;
    #pragma unroll
    for(int t=0;t<5;t++){
      int nc = cgrp*160 + t*32 + lo;
      if(nc < GG){ float d = acc[t][r] - mean[r]; s += d*d; }
    }
    for(int o=1;o<32;o<<=1) s += __shfl_xor(s,o,64);
    if(lo==0) sRed[lr][cgrp] = s;
  }
  __syncthreads();
  #pragma unroll
  for(int r=0;r<16;r++){
    int lr = rgrp*32 + (r&3) + 8*(r>>2) + 4*hi;
    size_t grow = (size_t)(b*NN + i0 + lr);
    float iv = 1.0f/sqrtf((sRed[lr][0]+sRed[lr][1])/(float)GG + 1e-5f);
    float mn = mean[r];
    #pragma unroll
    for(int t=0;t<5;t++){
      int nc = cgrp*160 + t*32 + lo;
      if(nc < GG){
        float y = fmaxf((acc[t][r]-mn)*iv*g[nc] + bt[nc], 0.f);
        bfout[grow*bf_ld + bf_off + nc] = f2bf(y);
      } else if(nc < bfpad){
        bfout[grow*bf_ld + bf_off + nc] = 0;
      }
    }
  }
}

// ---------------------------------------------------------------------------
extern "C" void kernel_launch(void* const* d_in, const int* in_sizes, int n_in,
                              void* d_out, int out_size, void* d_ws, size_t ws_size,
                              hipStream_t stream){
  const float* h     = (const float*)d_in[0];
  const float* amask = (const float*)d_in[1];
  const float *syn0_W=(const float*)d_in[2], *syn0_a1=(const float*)d_in[3], *syn0_a2=(const float*)d_in[4],
              *syn0_pos=(const float*)d_in[5], *syn0_tW=(const float*)d_in[6], *syn0_tb=(const float*)d_in[7],
              *syn0_g=(const float*)d_in[8], *syn0_b=(const float*)d_in[9];
  const float *syn1_W=(const float*)d_in[10], *syn1_a1=(const float*)d_in[11], *syn1_a2=(const float*)d_in[12],
              *syn1_pos=(const float*)d_in[13], *syn1_g=(const float*)d_in[14], *syn1_b=(const float*)d_in[15];
  const float *sem0_W=(const float*)d_in[16], *sem0_a1=(const float*)d_in[17], *sem0_a2=(const float*)d_in[18],
              *sem0_pos=(const float*)d_in[19], *sem0_tW=(const float*)d_in[20], *sem0_tb=(const float*)d_in[21],
              *sem0_g=(const float*)d_in[22], *sem0_b=(const float*)d_in[23];
  const float *sem1_W=(const float*)d_in[24], *sem1_a1=(const float*)d_in[25], *sem1_a2=(const float*)d_in[26],
              *sem1_pos=(const float*)d_in[27], *sem1_g=(const float*)d_in[28], *sem1_b=(const float*)d_in[29];
  const float *fus_W=(const float*)d_in[30], *fus_b=(const float*)d_in[31];
  const int* synadj    = (const int*)d_in[32];
  const int* positions = (const int*)d_in[33];
  float* out = (float*)d_out;

  float* ws   = (float*)d_ws;
  float* vvec = ws;                    // 16384
  float* Svec = vvec + 16384;          // 64
  float* f1   = Svec + 64;             // 16384
  float* f2   = f1 + 16384;            // 16384
  float* arep = f2 + 16384;            // 49152
  float* simb = arep + 49152;          // 16384
  float* T1_syn = simb + 16384;        // 4,915,200
  float* T1_sem = T1_syn + 4915200;    // 4,915,200
  short* Whb_syn = (short*)(T1_sem + 4915200);  // [16384][320]
  short* Whb_sem = Whb_syn + 5242880;
  short* Xb      = Whb_sem + 5242880;  // [16384][320]
  short* WhT     = Xb + 5242880;       // [64][320][256]
  short* Xf      = WhT + 5242880;      // [16384][608]
  short* Wt_all  = Xf + 9961472;       // [1280][768]
  short* Wt_syn1 = Wt_all + 983040;    // [320][320]
  short* Wt_sem1 = Wt_syn1 + 102400;
  short* Wt_fus  = Wt_sem1 + 102400;   // [320][608]
  // total ~104.4 MB

  dim3 gAttn(BB, 4), gWT(BB, 4);
  dim3 gG4(256, 4), gG1(256, 1);

  // semantic prep
  k_arep<<<dim3(BB,3),256,0,stream>>>(h, amask, arep);
  k_sim <<<dim3(BB,64),256,0,stream>>>(h, arep, simb);
  k_topk<<<BB,256,0,stream>>>(simb, vvec, Svec);

  // weight packs
  k_wcast4<<<3840,256,0,stream>>>(syn0_W, syn0_tW, sem0_W, sem0_tW, Wt_all);
  k_wcast<<<400,256,0,stream>>>(syn1_W, Wt_syn1, 300, 320, 320);
  k_wcast<<<400,256,0,stream>>>(sem1_W, Wt_sem1, 300, 320, 320);
  k_wcast<<<760,256,0,stream>>>(fus_W,  Wt_fus,  600, 608, 320);

  // merged layer-0 GEMM: both channels' Wh (bf16) + residuals (f32)
  k_gemm<768,3,float><<<gG4,256,0,stream>>>(h, Wt_all, positions,
      syn0_pos, sem0_pos, syn0_tb, sem0_tb,
      Whb_syn, Whb_sem, T1_syn, T1_sem, nullptr);

  // ---- syntactic channel ----
  k_whT<<<gWT,256,0,stream>>>(Whb_syn, syn0_a1, syn0_a2, WhT, f1, f2);
  k_attn_ln<false><<<gAttn,256,0,stream>>>(WhT, f1, f2, synadj, nullptr, nullptr,
      T1_syn, nullptr, syn0_g, syn0_b, Xb, 320, 0, 320);
  k_gemm<320,0,short><<<gG1,256,0,stream>>>(Xb, Wt_syn1, positions,
      syn1_pos, nullptr, nullptr, nullptr, Whb_syn, nullptr, nullptr, nullptr, nullptr);
  k_whT<<<gWT,256,0,stream>>>(Whb_syn, syn1_a1, syn1_a2, WhT, f1, f2);
  k_attn_ln<false><<<gAttn,256,0,stream>>>(WhT, f1, f2, synadj, nullptr, nullptr,
      nullptr, Xb, syn1_g, syn1_b, Xf, 608, 0, 300);

  // ---- semantic channel ----
  k_whT<<<gWT,256,0,stream>>>(Whb_sem, sem0_a1, sem0_a2, WhT, f1, f2);
  k_attn_ln<true><<<gAttn,256,0,stream>>>(WhT, f1, f2, nullptr, vvec, Svec,
      T1_sem, nullptr, sem0_g, sem0_b, Xb, 320, 0, 320);
  k_gemm<320,0,short><<<gG1,256,0,stream>>>(Xb, Wt_sem1, positions,
      sem1_pos, nullptr, nullptr, nullptr, Whb_sem, nullptr, nullptr, nullptr, nullptr);
  k_whT<<<gWT,256,0,stream>>>(Whb_sem, sem1_a1, sem1_a2, WhT, f1, f2);
  k_attn_ln<true><<<gAttn,256,0,stream>>>(WhT, f1, f2, nullptr, vvec, Svec,
      nullptr, Xb, sem1_g, sem1_b, Xf, 608, 300, 308);

  // fusion: out = relu(concat @ fus_W + fus_b)
  k_gemm<608,2,short><<<gG1,256,0,stream>>>(Xf, Wt_fus, positions,
      nullptr, nullptr, fus_b, nullptr, nullptr, nullptr, nullptr, nullptr, out);
}

// Round 10
// 722.328 us; speedup vs baseline: 1.2659x; 1.0380x over previous
//
#include <hip/hip_runtime.h>
#include <hip/hip_bf16.h>
#include <math.h>

#define BB 64
#define NN 256
#define DD 768
#define GG 300
#define KK 10
#define NEGV -9e15f

typedef __attribute__((ext_vector_type(8)))  short short8;
typedef __attribute__((ext_vector_type(4)))  short short4v;
typedef __attribute__((ext_vector_type(16))) float f32x16;

static __device__ __forceinline__ short f2bf(float f){
  __hip_bfloat16 b = __float2bfloat16(f);
  return __builtin_bit_cast(short, b);
}
static __device__ __forceinline__ float bf2f(short s){
  return __bfloat162float(__builtin_bit_cast(__hip_bfloat16, s));
}

// async global->LDS DMA, 16B per lane; dst is wave-uniform base (+lane*16 by HW)
static __device__ __forceinline__ void dma16(const void* g, void* l){
  __builtin_amdgcn_global_load_lds((const __attribute__((address_space(1))) void*)g,
                                   (__attribute__((address_space(3))) void*)l, 16, 0, 0);
}

__device__ __forceinline__ float blkReduceSum(float v, float* s){
  for(int o=32;o>0;o>>=1) v += __shfl_down(v,o,64);
  int nw = blockDim.x>>6;
  __syncthreads();
  if((threadIdx.x&63)==0) s[threadIdx.x>>6]=v;
  __syncthreads();
  float r=s[0];
  for(int i=1;i<nw;i++) r+=s[i];
  return r;
}

// ---------------------------------------------------------------------------
// Semantic prep A: arep[b][d] = masked mean of h over nodes. grid (64,3).
// ---------------------------------------------------------------------------
__global__ __launch_bounds__(256) void k_arep(const float* __restrict__ h,
    const float* __restrict__ amask, float* __restrict__ arep){
  int b = blockIdx.x, tid = threadIdx.x;
  int d = blockIdx.y*256 + tid;
  __shared__ float s_mask[NN];
  __shared__ float s_red[4];
  s_mask[tid] = amask[b*NN+tid];
  float cnt = blkReduceSum(s_mask[tid], s_red);
  const float* hb = h + (size_t)b*NN*DD + d;
  float a = 0.f;
  #pragma unroll 8
  for(int n=0;n<NN;n++) a += hb[(size_t)n*DD] * s_mask[n];
  arep[b*DD + d] = a/(cnt+1e-8f);
}

// ---------------------------------------------------------------------------
// Semantic prep B: sim[b][n] = cos(h[b,n,:], arep[b,:]). grid (64,64).
// ---------------------------------------------------------------------------
__global__ __launch_bounds__(256) void k_sim(const float* __restrict__ h,
    const float* __restrict__ arep, float* __restrict__ sim){
  int b = blockIdx.x, tid = threadIdx.x;
  int lane = tid&63, w = tid>>6;
  __shared__ __align__(16) float s_a[DD];
  __shared__ float s_red[4];
  float pa = 0.f;
  for(int d=tid; d<DD; d+=256){ float v = arep[b*DD+d]; s_a[d]=v; pa += v*v; }
  float na = blkReduceSum(pa, s_red);
  float nac = fmaxf(sqrtf(na), 1e-12f);
  int node = blockIdx.y*4 + w;
  const float* hr = h + ((size_t)b*NN+node)*DD;
  float dot=0.f, nn=0.f;
  #pragma unroll
  for(int q=0;q<3;q++){
    int c = lane*4 + q*256;
    float4 hv = *(const float4*)(hr + c);
    float4 av = *(const float4*)(s_a + c);
    dot += hv.x*av.x + hv.y*av.y + hv.z*av.z + hv.w*av.w;
    nn  += hv.x*hv.x + hv.y*hv.y + hv.z*hv.z + hv.w*hv.w;
  }
  for(int o=32;o>0;o>>=1){ dot += __shfl_down(dot,o,64); nn += __shfl_down(nn,o,64); }
  if(lane==0){
    nn = fmaxf(sqrtf(nn), 1e-12f);
    sim[b*NN+node] = dot/(nn*nac);
  }
}

// ---------------------------------------------------------------------------
// Semantic prep C: stable top-K per batch -> scattered v[b,:], S[b].
// ---------------------------------------------------------------------------
__global__ __launch_bounds__(256) void k_topk(const float* __restrict__ sim,
    float* __restrict__ vout, float* __restrict__ Sout){
  int b = blockIdx.x, tid = threadIdx.x;
  __shared__ float s_bv[4]; __shared__ int s_bi[4];
  __shared__ float s_tv[KK]; __shared__ int s_ti[KK];
  __shared__ float s_v[NN];
  float v = sim[b*NN+tid];
  int lane = tid&63, w = tid>>6;
  for(int k=0;k<KK;k++){
    float bv = v; int bi_ = tid;
    for(int o=32;o>0;o>>=1){
      float ov = __shfl_down(bv,o,64); int oi = __shfl_down(bi_,o,64);
      if(ov>bv || (ov==bv && oi<bi_)){ bv=ov; bi_=oi; }
    }
    if(lane==0){ s_bv[w]=bv; s_bi[w]=bi_; }
    __syncthreads();
    float gb = s_bv[0]; int gi = s_bi[0];
    for(int i=1;i<4;i++){ if(s_bv[i]>gb || (s_bv[i]==gb && s_bi[i]<gi)){ gb=s_bv[i]; gi=s_bi[i]; } }
    if(tid==0){ s_tv[k]=gb; s_ti[k]=gi; }
    if(tid==gi) v = -1e30f;
    __syncthreads();
  }
  s_v[tid]=0.f;
  __syncthreads();
  if(tid<KK) s_v[s_ti[tid]] = s_tv[tid];
  __syncthreads();
  float S=0.f;
  for(int k=0;k<KK;k++) S += s_tv[k];
  vout[b*NN+tid] = s_v[tid];
  if(tid==0) Sout[b] = S;
}

// ---------------------------------------------------------------------------
// Weight cast+transpose+pad: dst[n][k] bf16 [NPAD][KPAD] from W[k][300].
// ---------------------------------------------------------------------------
__global__ __launch_bounds__(256) void k_wcast(const float* __restrict__ W1,
    short* __restrict__ dst, int K, int KPAD, int NPAD){
  int idx = blockIdx.x*256 + threadIdx.x;
  if(idx >= NPAD*KPAD) return;
  int n = idx / KPAD, k = idx % KPAD;
  float v = (k < K && n < 300) ? W1[(size_t)k*300 + n] : 0.f;
  dst[idx] = f2bf(v);
}

// Quad pack for merged layer-0 GEMM: dst [1280][768], 4 segments of 320 rows:
// {syn0_W, syn0_tW, sem0_W, sem0_tW}, each 300 used + 20 zero pad.
__global__ __launch_bounds__(256) void k_wcast4(const float* __restrict__ W0,
    const float* __restrict__ W1, const float* __restrict__ W2,
    const float* __restrict__ W3, short* __restrict__ dst){
  int idx = blockIdx.x*256 + threadIdx.x;
  if(idx >= 1280*768) return;
  int n = idx / 768, k = idx - (n*768);
  int seg = n/320; int nl = n - seg*320;
  const float* src = (seg==0)?W0 : (seg==1)?W1 : (seg==2)?W2 : W3;
  float v = (nl<300) ? src[(size_t)k*300 + nl] : 0.f;
  dst[idx] = f2bf(v);
}

// ---------------------------------------------------------------------------
// MFMA GEMM. Y = X[M][KPAD] @ Wt^T, Wt[NPAD][KPAD] bf16. BM=64, BN=320, BK=32.
// B via global_load_lds DMA, unpadded [320][32] LDS, XOR-granule swizzle.
// __launch_bounds__(256,4) -> 4 blocks/CU. Folded f1/f2 in epilogue.
// ROUND-9 BUG FIX: f1/f2 row-dot partials come from TWO waves per row
// (cgrp 0: cols 0-159, cgrp 1: cols 160-299); round 9 raced both into
// f1o[row] (half the dot). Now staged in sF1/sF2[64][2] and combined.
// ---------------------------------------------------------------------------
template<int KPAD, int MODE, typename XT>
__global__ __launch_bounds__(256,4) void k_gemm(const XT* __restrict__ X,
    const short* __restrict__ Bt, const int* __restrict__ positions,
    const float* __restrict__ posA, const float* __restrict__ posB,
    const float* __restrict__ tbA, const float* __restrict__ tbB,
    const float* __restrict__ a1A, const float* __restrict__ a2A,
    const float* __restrict__ a1B, const float* __restrict__ a2B,
    short* __restrict__ whbA, short* __restrict__ whbB,
    float* __restrict__ t1A, float* __restrict__ t1B,
    float* __restrict__ f1A, float* __restrict__ f2A,
    float* __restrict__ f1B, float* __restrict__ f2B,
    float* __restrict__ outf){
  __shared__ __align__(16) short sX[64*40];
  __shared__ __align__(16) short sB[320*32];
  __shared__ float sF1[64][2], sF2[64][2];
  const int tid = threadIdx.x;
  const int lane = tid & 63, wave = tid >> 6;
  const int rgrp = wave & 1, cgrp = wave >> 1;
  const int row0 = blockIdx.x * 64;
  const int ncol0 = blockIdx.y * 320;
  const int lo = lane & 31, hi = lane >> 5;
  constexpr int NIT = KPAD/32;
  const int phase = (int)((blockIdx.x*7 + blockIdx.y*3) % NIT);
  const int drow = lane>>2;                    // 0..15
  const int dk   = ((lane&3) ^ (drow&3))*8;    // swizzled k-offset (shorts)

  f32x16 acc[5];
  #pragma unroll
  for(int t=0;t<5;t++)
    #pragma unroll
    for(int i=0;i<16;i++) acc[t][i] = 0.f;

  float4 rx0, rx1;
  if constexpr (sizeof(XT)==4){
    int k0 = phase*32;
    int c0=tid, c1=tid+256;
    rx0 = *(const float4*)(X + (size_t)(row0+(c0>>3))*KPAD + k0 + (c0&7)*4);
    rx1 = *(const float4*)(X + (size_t)(row0+(c1>>3))*KPAD + k0 + (c1&7)*4);
  }

  for(int it=0; it<NIT; it++){
    int kv = it + phase; if(kv >= NIT) kv -= NIT;
    int k0 = kv*32;
    if constexpr (sizeof(XT)==4){
      { int c=tid; short4v s; s.x=f2bf(rx0.x); s.y=f2bf(rx0.y); s.z=f2bf(rx0.z); s.w=f2bf(rx0.w);
        *(short4v*)(sX + (c>>3)*40 + (c&7)*4) = s; }
      { int c=tid+256; short4v s; s.x=f2bf(rx1.x); s.y=f2bf(rx1.y); s.z=f2bf(rx1.z); s.w=f2bf(rx1.w);
        *(short4v*)(sX + (c>>3)*40 + (c&7)*4) = s; }
    } else {
      dma16(X + (size_t)(row0 + wave*16 + drow)*KPAD + k0 + dk, sX + wave*512);
    }
    #pragma unroll
    for(int u=0;u<5;u++){
      int q = wave*5+u;
      dma16(Bt + (size_t)(ncol0 + q*16 + drow)*KPAD + k0 + dk, sB + q*512);
    }
    __syncthreads();
    if constexpr (sizeof(XT)==4){
      if(it+1 < NIT){
        int kn = it+1+phase; if(kn >= NIT) kn -= NIT;
        int k1 = kn*32;
        int c0=tid, c1=tid+256;
        rx0 = *(const float4*)(X + (size_t)(row0+(c0>>3))*KPAD + k1 + (c0&7)*4);
        rx1 = *(const float4*)(X + (size_t)(row0+(c1>>3))*KPAD + k1 + (c1&7)*4);
      }
    }
    #pragma unroll
    for(int ss=0; ss<2; ss++){
      short8 a;
      if constexpr (sizeof(XT)==4){
        a = *(const short8*)(sX + (rgrp*32 + lo)*40 + ss*16 + hi*8);
      } else {
        a = *(const short8*)(sX + (rgrp*32 + lo)*32 + (((ss*2+hi)^(lo&3))*8));
      }
      #pragma unroll
      for(int t=0;t<5;t++){
        short8 b = *(const short8*)(sB + (cgrp*160 + t*32 + lo)*32 + (((ss*2+hi)^(lo&3))*8));
        acc[t] = __builtin_amdgcn_mfma_f32_32x32x16_bf16(a, b, acc[t], 0, 0, 0);
      }
    }
    __syncthreads();
  }

  // ---- epilogue ----
  const int seg = (MODE==3) ? blockIdx.y : 0;
  const bool fold = (MODE==0) || (MODE==3 && (seg==0 || seg==2));
  float* sAv = (float*)sB;   // reuse LDS for a1/a2 cache (last barrier passed)
  if(fold){
    const float* a1v = (MODE==3 && seg==2) ? a1B : a1A;
    const float* a2v = (MODE==3 && seg==2) ? a2B : a2A;
    for(int c=tid; c<300; c+=256){ sAv[c] = a1v[c]; sAv[c+300] = a2v[c]; }
    __syncthreads();
  }
  #pragma unroll
  for(int r=0;r<16;r++){
    int lr = rgrp*32 + (r&3) + 8*(r>>2) + 4*hi;
    int row = row0 + lr;
    int p = (MODE!=2) ? positions[row] : 0;
    float s1=0.f, s2=0.f;
    #pragma unroll
    for(int t=0;t<5;t++){
      int nc = cgrp*160 + t*32 + lo;
      float v = acc[t][r];
      if(nc < 300){
        if(MODE==2){
          outf[(size_t)row*300 + nc] = fmaxf(v + tbA[nc], 0.f);
        } else if(MODE==0){
          float y = v + posA[(size_t)p*300 + nc];
          whbA[(size_t)row*320 + nc] = f2bf(y);
          s1 += y*sAv[nc]; s2 += y*sAv[300+nc];
        } else { // MODE 3
          if(seg==0){
            float y = v + posA[(size_t)p*300 + nc];
            whbA[(size_t)row*320 + nc] = f2bf(y);
            s1 += y*sAv[nc]; s2 += y*sAv[300+nc];
          } else if(seg==1){
            t1A[(size_t)row*300 + nc] = v + tbA[nc];
          } else if(seg==2){
            float y = v + posB[(size_t)p*300 + nc];
            whbB[(size_t)row*320 + nc] = f2bf(y);
            s1 += y*sAv[nc]; s2 += y*sAv[300+nc];
          } else {
            t1B[(size_t)row*300 + nc] = v + tbB[nc];
          }
        }
      }
    }
    if(fold){
      for(int o=1;o<32;o<<=1){ s1 += __shfl_xor(s1,o,64); s2 += __shfl_xor(s2,o,64); }
      if(lo==0){ sF1[lr][cgrp] = s1; sF2[lr][cgrp] = s2; }
    }
  }
  if(fold){
    __syncthreads();
    if(tid < 64){
      float* f1o = (MODE==3 && seg==2) ? f1B : f1A;
      float* f2o = (MODE==3 && seg==2) ? f2B : f2A;
      f1o[row0+tid] = sF1[tid][0] + sF1[tid][1];
      f2o[row0+tid] = sF2[tid][0] + sF2[tid][1];
    }
  }
}

// ---------------------------------------------------------------------------
// Pure Wh transpose: WhT[b][n(320)][j(256)] bf16 from Whb[row][320] bf16.
// ---------------------------------------------------------------------------
__global__ __launch_bounds__(256) void k_whT(const short* __restrict__ Whb,
    short* __restrict__ WhT){
  __shared__ short s_t[64][308];
  int b = blockIdx.x, j0 = blockIdx.y*64, tid = threadIdx.x;
  for(int c=tid; c<64*300; c+=256){
    int r = c/300, n = c - r*300;
    s_t[r][n] = Whb[((size_t)(b*NN + j0 + r))*320 + n];
  }
  __syncthreads();
  for(int c=tid; c<320*64; c+=256){
    int n = c>>6, jj = c&63;
    WhT[((size_t)b*320 + n)*256 + j0 + jj] = (n<GG) ? s_t[jj][n] : (short)0;
  }
}

// ---------------------------------------------------------------------------
// Fused attention (MFMA) + residual + LayerNorm + ReLU. grid (64,4), 256 thr.
// ---------------------------------------------------------------------------
template<bool SEM>
__global__ __launch_bounds__(256) void k_attn_ln(
    const short* __restrict__ WhT,
    const float* __restrict__ f1, const float* __restrict__ f2,
    const int* __restrict__ adjI, const float* __restrict__ vvec,
    const float* __restrict__ Svec,
    const float* __restrict__ resf, const short* __restrict__ resb,
    const float* __restrict__ g, const float* __restrict__ bt,
    short* __restrict__ bfout, int bf_ld, int bf_off, int bfpad){
  int b = blockIdx.x, i0 = blockIdx.y*64, tid = threadIdx.x;
  int lane = tid&63, wave = tid>>6;
  int lo = lane&31, hi = lane>>5;
  int rgrp = wave&1, cgrp = wave>>1;

  __shared__ float s_f2[NN];
  __shared__ float s_v[NN];
  __shared__ float s_inv[64];
  __shared__ float sRed[64][2];
  __shared__ __align__(16) short sP[64][264];
  __shared__ __align__(16) short sB[320*40];

  s_f2[tid] = f2[b*NN+tid];
  float S = 0.f;
  if(SEM){ s_v[tid] = vvec[b*NN+tid]; S = Svec[b]; }
  __syncthreads();

  {
    int r = tid>>2, q = tid&3, i = i0 + r;
    float fi = f1[b*NN+i];
    float vi = 0.f, denom = 0.f;
    if(SEM){ vi = s_v[i]; denom = 0.5f*((float)NN*vi + S) + 1.f + 1e-8f; }
    const int* arow = adjI ? (adjI + ((size_t)b*NN+i)*NN + q*64) : (const int*)0;
    float s = 0.f;
    #pragma unroll
    for(int c=0;c<8;c++){
      int jb = q*64 + c*8;
      int4 a0, a1_;
      if(!SEM){ a0 = *(const int4*)(arow + c*8); a1_ = *(const int4*)(arow + c*8 + 4); }
      short8 ps;
      #pragma unroll
      for(int k=0;k<8;k++){
        int j = jb + k;
        float ee = fi + s_f2[j];
        ee = ee>0.f ? ee : 0.2f*ee;
        bool m;
        if(SEM){
          float val = 0.5f*(vi + s_v[j]) + (i==j ? 1.f : 0.f);
          m = (denom > 0.f) ? (val > 0.f) : (val < 0.f);
        } else {
          m = ((k<4) ? (&a0.x)[k] : (&a1_.x)[k-4]) > 0;
        }
        float pv = m ? __expf(ee) : 0.f;
        s += pv;
        ps[k] = f2bf(pv);
      }
      *(short8*)&sP[r][jb] = ps;
    }
    s += __shfl_xor(s,1,64);
    s += __shfl_xor(s,2,64);
    if(q==0) s_inv[r] = 1.f/s;
  }
  __syncthreads();

  f32x16 acc[5];
  #pragma unroll
  for(int t=0;t<5;t++)
    #pragma unroll
    for(int i=0;i<16;i++) acc[t][i] = 0.f;

  const short* wtb = WhT + (size_t)b*320*256;
  for(int k0=0; k0<256; k0+=32){
    #pragma unroll
    for(int u=0;u<5;u++){
      int c = tid + u*256; int r=c>>2, cc=c&3;
      *(short8*)(sB + r*40 + cc*8) = *(const short8*)(wtb + (size_t)r*256 + k0 + cc*8);
    }
    __syncthreads();
    #pragma unroll
    for(int ss=0; ss<2; ss++){
      short8 a = *(const short8*)&sP[rgrp*32 + lo][k0 + ss*16 + hi*8];
      #pragma unroll
      for(int t=0;t<5;t++){
        short8 bb = *(const short8*)(sB + (cgrp*160 + t*32 + lo)*40 + ss*16 + hi*8);
        acc[t] = __builtin_amdgcn_mfma_f32_32x32x16_bf16(a, bb, acc[t], 0, 0, 0);
      }
    }
    __syncthreads();
  }

  #pragma unroll
  for(int r=0;r<16;r++){
    int lr = rgrp*32 + (r&3) + 8*(r>>2) + 4*hi;
    float inv_s = s_inv[lr];
    size_t grow = (size_t)(b*NN + i0 + lr);
    float sum = 0.f;
    #pragma unroll
    for(int t=0;t<5;t++){
      int nc = cgrp*160 + t*32 + lo;
      float x = 0.f;
      if(nc < GG){
        float rv = resf ? resf[grow*300 + nc] : bf2f(resb[grow*320 + nc]);
        x = acc[t][r]*inv_s + rv;
      }
      acc[t][r] = x; sum += x;
    }
    for(int o=1;o<32;o<<=1) sum += __shfl_xor(sum,o,64);
    if(lo==0) sRed[lr][cgrp] = sum;
  }
  __syncthreads();
  float mean[16];
  #pragma unroll
  for(int r=0;r<16;r++){
    int lr = rgrp*32 + (r&3) + 8*(r>>2) + 4*hi;
    mean[r] = (sRed[lr][0] + sRed[lr][1]) * (1.f/(float)GG);
  }
  __syncthreads();
  #pragma unroll
  for(int r=0;r<16;r++){
    int lr = rgrp*32 + (r&3) + 8*(r>>2) + 4*hi;
    float s = 0.f;
    #pragma unroll
    for(int t=0;t<5;t++){
      int nc = cgrp*160 + t*32 + lo;
      if(nc < GG){ float d = acc[t][r] - mean[r]; s += d*d; }
    }
    for(int o=1;o<32;o<<=1) s += __shfl_xor(s,o,64);
    if(lo==0) sRed[lr][cgrp] = s;
  }
  __syncthreads();
  #pragma unroll
  for(int r=0;r<16;r++){
    int lr = rgrp*32 + (r&3) + 8*(r>>2) + 4*hi;
    size_t grow = (size_t)(b*NN + i0 + lr);
    float iv = 1.0f/sqrtf((sRed[lr][0]+sRed[lr][1])/(float)GG + 1e-5f);
    float mn = mean[r];
    #pragma unroll
    for(int t=0;t<5;t++){
      int nc = cgrp*160 + t*32 + lo;
      if(nc < GG){
        float y = fmaxf((acc[t][r]-mn)*iv*g[nc] + bt[nc], 0.f);
        bfout[grow*bf_ld + bf_off + nc] = f2bf(y);
      } else if(nc < bfpad){
        bfout[grow*bf_ld + bf_off + nc] = 0;
      }
    }
  }
}

// ---------------------------------------------------------------------------
extern "C" void kernel_launch(void* const* d_in, const int* in_sizes, int n_in,
                              void* d_out, int out_size, void* d_ws, size_t ws_size,
                              hipStream_t stream){
  const float* h     = (const float*)d_in[0];
  const float* amask = (const float*)d_in[1];
  const float *syn0_W=(const float*)d_in[2], *syn0_a1=(const float*)d_in[3], *syn0_a2=(const float*)d_in[4],
              *syn0_pos=(const float*)d_in[5], *syn0_tW=(const float*)d_in[6], *syn0_tb=(const float*)d_in[7],
              *syn0_g=(const float*)d_in[8], *syn0_b=(const float*)d_in[9];
  const float *syn1_W=(const float*)d_in[10], *syn1_a1=(const float*)d_in[11], *syn1_a2=(const float*)d_in[12],
              *syn1_pos=(const float*)d_in[13], *syn1_g=(const float*)d_in[14], *syn1_b=(const float*)d_in[15];
  const float *sem0_W=(const float*)d_in[16], *sem0_a1=(const float*)d_in[17], *sem0_a2=(const float*)d_in[18],
              *sem0_pos=(const float*)d_in[19], *sem0_tW=(const float*)d_in[20], *sem0_tb=(const float*)d_in[21],
              *sem0_g=(const float*)d_in[22], *sem0_b=(const float*)d_in[23];
  const float *sem1_W=(const float*)d_in[24], *sem1_a1=(const float*)d_in[25], *sem1_a2=(const float*)d_in[26],
              *sem1_pos=(const float*)d_in[27], *sem1_g=(const float*)d_in[28], *sem1_b=(const float*)d_in[29];
  const float *fus_W=(const float*)d_in[30], *fus_b=(const float*)d_in[31];
  const int* synadj    = (const int*)d_in[32];
  const int* positions = (const int*)d_in[33];
  float* out = (float*)d_out;

  float* ws   = (float*)d_ws;
  float* vvec = ws;                    // 16384
  float* Svec = vvec + 16384;          // 64
  float* f1a  = Svec + 64;             // 16384
  float* f2a  = f1a + 16384;           // 16384
  float* f1b  = f2a + 16384;           // 16384
  float* f2b  = f1b + 16384;           // 16384
  float* arep = f2b + 16384;           // 49152
  float* simb = arep + 49152;          // 16384
  float* T1_syn = simb + 16384;        // 4,915,200
  float* T1_sem = T1_syn + 4915200;    // 4,915,200
  short* Whb_syn = (short*)(T1_sem + 4915200);  // [16384][320]
  short* Whb_sem = Whb_syn + 5242880;
  short* Xb      = Whb_sem + 5242880;  // [16384][320]
  short* WhT     = Xb + 5242880;       // [64][320][256]
  short* Xf      = WhT + 5242880;      // [16384][608]
  short* Wt_all  = Xf + 9961472;       // [1280][768]
  short* Wt_syn1 = Wt_all + 983040;    // [320][320]
  short* Wt_sem1 = Wt_syn1 + 102400;
  short* Wt_fus  = Wt_sem1 + 102400;   // [320][608]

  dim3 gAttn(BB, 4), gWT(BB, 4);
  dim3 gG4(256, 4), gG1(256, 1);

  // semantic prep
  k_arep<<<dim3(BB,3),256,0,stream>>>(h, amask, arep);
  k_sim <<<dim3(BB,64),256,0,stream>>>(h, arep, simb);
  k_topk<<<BB,256,0,stream>>>(simb, vvec, Svec);

  // weight packs
  k_wcast4<<<3840,256,0,stream>>>(syn0_W, syn0_tW, sem0_W, sem0_tW, Wt_all);
  k_wcast<<<400,256,0,stream>>>(syn1_W, Wt_syn1, 300, 320, 320);
  k_wcast<<<400,256,0,stream>>>(sem1_W, Wt_sem1, 300, 320, 320);
  k_wcast<<<760,256,0,stream>>>(fus_W,  Wt_fus,  600, 608, 320);

  // merged layer-0 GEMM: Wh (bf16) + residuals (f32) + folded f1/f2 per channel
  k_gemm<768,3,float><<<gG4,256,0,stream>>>(h, Wt_all, positions,
      syn0_pos, sem0_pos, syn0_tb, sem0_tb,
      syn0_a1, syn0_a2, sem0_a1, sem0_a2,
      Whb_syn, Whb_sem, T1_syn, T1_sem,
      f1a, f2a, f1b, f2b, nullptr);

  // ---- syntactic channel ----
  k_whT<<<gWT,256,0,stream>>>(Whb_syn, WhT);
  k_attn_ln<false><<<gAttn,256,0,stream>>>(WhT, f1a, f2a, synadj, nullptr, nullptr,
      T1_syn, nullptr, syn0_g, syn0_b, Xb, 320, 0, 320);
  k_gemm<320,0,short><<<gG1,256,0,stream>>>(Xb, Wt_syn1, positions,
      syn1_pos, nullptr, nullptr, nullptr,
      syn1_a1, syn1_a2, nullptr, nullptr,
      Whb_syn, nullptr, nullptr, nullptr,
      f1a, f2a, nullptr, nullptr, nullptr);
  k_whT<<<gWT,256,0,stream>>>(Whb_syn, WhT);
  k_attn_ln<false><<<gAttn,256,0,stream>>>(WhT, f1a, f2a, synadj, nullptr, nullptr,
      nullptr, Xb, syn1_g, syn1_b, Xf, 608, 0, 300);

  // ---- semantic channel ----
  k_whT<<<gWT,256,0,stream>>>(Whb_sem, WhT);
  k_attn_ln<true><<<gAttn,256,0,stream>>>(WhT, f1b, f2b, nullptr, vvec, Svec,
      T1_sem, nullptr, sem0_g, sem0_b, Xb, 320, 0, 320);
  k_gemm<320,0,short><<<gG1,256,0,stream>>>(Xb, Wt_sem1, positions,
      sem1_pos, nullptr, nullptr, nullptr,
      sem1_a1, sem1_a2, nullptr, nullptr,
      Whb_sem, nullptr, nullptr, nullptr,
      f1b, f2b, nullptr, nullptr, nullptr);
  k_whT<<<gWT,256,0,stream>>>(Whb_sem, WhT);
  k_attn_ln<true><<<gAttn,256,0,stream>>>(WhT, f1b, f2b, nullptr, vvec, Svec,
      nullptr, Xb, sem1_g, sem1_b, Xf, 608, 300, 308);

  // fusion: out = relu(concat @ fus_W + fus_b)
  k_gemm<608,2,short><<<gG1,256,0,stream>>>(Xf, Wt_fus, positions,
      nullptr, nullptr, fus_b, nullptr,
      nullptr, nullptr, nullptr, nullptr,
      nullptr, nullptr, nullptr, nullptr,
      nullptr, nullptr, nullptr, nullptr, out);
}